// Round 3
// baseline (218.271 us; speedup 1.0000x reference)
//
#include <hip/hip_runtime.h>
#include <hip/hip_fp16.h>
#include <hip/hip_cooperative_groups.h>
#include <stdint.h>

namespace cg = cooperative_groups;

#define D0 1024
#define D1 8192
#define D2 8192
#define D3 10240
#define B_ROWS 4096

// LDS layout (bytes), 8 rows fp16 row-interleaved [gate][8 rows]=16B:
// xb 16K | h2 128K | csum 320 -> 144.3 KB, 1 block/CU. One block covers
// 16 rows in two pipelined 8-row passes.
#define SM_XB     0
#define SM_H2     16384
#define SM_CSUM   (16384 + 131072)
#define SM_BYTES  (16384 + 131072 + 320)

// prep tasks: 3 softmax roles per D2 gate + 1 per D3 gate.
// 34816 = 136 * 256 -> exactly 136 tasks per block, perfectly balanced.
#define PREP_TOTAL (3 * D2 + D3)
#define PREP_PER_BLOCK 136

// softmax(w[16]) @ OP_COEF -> (c0,c1,c2,c3)
__device__ __forceinline__ float4 softmax_coef(const float* __restrict__ w) {
    const float4* wv = (const float4*)w;
    float4 q0 = wv[0], q1 = wv[1], q2 = wv[2], q3 = wv[3];
    float wa[16] = {q0.x, q0.y, q0.z, q0.w, q1.x, q1.y, q1.z, q1.w,
                    q2.x, q2.y, q2.z, q2.w, q3.x, q3.y, q3.z, q3.w};
    float m = wa[0];
#pragma unroll
    for (int i = 1; i < 16; ++i) m = fmaxf(m, wa[i]);
    float e[16], s = 0.f;
#pragma unroll
    for (int i = 0; i < 16; ++i) { e[i] = __expf(wa[i] - m); s += e[i]; }
    float inv = 1.f / s;
    static constexpr float OPC[16][4] = {
        {0.f, 0.f, 0.f, 0.f}, {0.f, 0.f, 0.f, 1.f}, {0.f, 1.f, 0.f, -1.f}, {0.f, 1.f, 0.f, 0.f},
        {0.f, 0.f, 1.f, -1.f}, {0.f, 0.f, 1.f, 0.f}, {0.f, 1.f, 1.f, -2.f}, {0.f, 1.f, 1.f, -1.f},
        {1.f, -1.f, -1.f, 1.f}, {1.f, -1.f, -1.f, 2.f}, {1.f, 0.f, -1.f, 0.f}, {1.f, 0.f, -1.f, 1.f},
        {1.f, -1.f, 0.f, 0.f}, {1.f, -1.f, 0.f, 1.f}, {1.f, 0.f, 0.f, -1.f}, {1.f, 0.f, 0.f, 0.f}};
    float c0 = 0.f, c1 = 0.f, c2 = 0.f, c3 = 0.f;
#pragma unroll
    for (int i = 0; i < 16; ++i) {  // 0/±1/±2 multiplies fold at compile time
        float p = e[i] * inv;
        c0 += p * OPC[i][0];
        c1 += p * OPC[i][1];
        c2 += p * OPC[i][2];
        c3 += p * OPC[i][3];
    }
    return make_float4(c0, c1, c2, c3);
}

__device__ __forceinline__ uint2 pack_coef(float4 c) {
    uint2 r;
    r.x = __builtin_bit_cast(uint32_t, __floats2half2_rn(c.x, c.y));
    r.y = __builtin_bit_cast(uint32_t, __floats2half2_rn(c.z, c.w));
    return r;
}

// One gate for 8 rows (4x half2); compact coefs (c0c1, c2c3) broadcast here.
// h = (c0 + c2*b) + a*(c1 + c3*b): 12 v_pk_fma_f16 + 4 extracts.
__device__ __forceinline__ uint4 gate8(uint4 av, uint4 bv, uint2 cf) {
    __half2 p = __builtin_bit_cast(__half2, cf.x);  // (c0,c1)
    __half2 q = __builtin_bit_cast(__half2, cf.y);  // (c2,c3)
    __half2 c0 = __low2half2(p), c1 = __high2half2(p);
    __half2 c2 = __low2half2(q), c3 = __high2half2(q);
    uint4 r;
#pragma unroll
    for (int i = 0; i < 4; ++i) {
        __half2 a = __builtin_bit_cast(__half2, (&av.x)[i]);
        __half2 b = __builtin_bit_cast(__half2, (&bv.x)[i]);
        __half2 h = __hfma2(a, __hfma2(b, c3, c1), __hfma2(b, c2, c0));
        (&r.x)[i] = __builtin_bit_cast(uint32_t, h);
    }
    return r;
}

// Full-wave f32 sum on the VALU pipe via DPP (row_shr 1/2/4/8 +
// row_bcast 15/31); result valid in lane 63. Keeps the reduction off the
// LDS pipe (the fused kernel's contended resource).
__device__ __forceinline__ float dpp_sum_f32(float x) {
#define DPPADD(ctrl, rmask)                                              \
    x += __builtin_bit_cast(float, __builtin_amdgcn_update_dpp(          \
             0, __builtin_bit_cast(int, x), (ctrl), (rmask), 0xf, true))
    DPPADD(0x111, 0xf);  // row_shr:1
    DPPADD(0x112, 0xf);  // row_shr:2
    DPPADD(0x114, 0xf);  // row_shr:4
    DPPADD(0x118, 0xf);  // row_shr:8  -> lane15 of each row = row sum
    DPPADD(0x142, 0xa);  // row_bcast:15 into rows 1,3
    DPPADD(0x143, 0xc);  // row_bcast:31 into rows 2,3 -> lane63 = total
#undef DPPADD
    return x;
}

// Stage BC body for one 8-row pass: fused layers 1+2.
// Gate map: thread t, iter k handles gates t + 2048k and t + 2048k + 1024
// -> h2 writes lane-linear (conflict-free), metadata loads 16B/lane coalesced.
__device__ __forceinline__ void stage_bc(char* sm, int t,
                                         const uint4* __restrict__ bcM1,
                                         const uint4* __restrict__ bcM2,
                                         uint4 m1a_n, uint4 m1b_n) {
#pragma unroll
    for (int k = 0; k < 4; ++k) {
        uint4 m1a = m1a_n, m1b = m1b_n;
        int g0 = t + (k << 11);       // + 2048k
        int g1 = g0 + 1024;
        uint4 m2a = bcM2[g0];
        uint4 m2b = bcM2[g1];
        if (k < 3) {  // depth-2 prefetch of the gather-address stream
            m1a_n = bcM1[g0 + 2048];
            m1b_n = bcM1[g1 + 2048];
        }
        // 8 independent b128 gathers in flight.
        uint4 aa0 = *(const uint4*)(sm + (m1a.x & 0xffffu));
        uint4 ab0 = *(const uint4*)(sm + (m1a.x >> 16));
        uint4 ba0 = *(const uint4*)(sm + (m1a.y & 0xffffu));
        uint4 bb0 = *(const uint4*)(sm + (m1a.y >> 16));
        uint4 aa1 = *(const uint4*)(sm + (m1b.x & 0xffffu));
        uint4 ab1 = *(const uint4*)(sm + (m1b.x >> 16));
        uint4 ba1 = *(const uint4*)(sm + (m1b.y & 0xffffu));
        uint4 bb1 = *(const uint4*)(sm + (m1b.y >> 16));
        uint4 h0 = gate8(gate8(aa0, ab0, make_uint2(m2a.x, m2a.y)),
                         gate8(ba0, bb0, make_uint2(m2a.z, m2a.w)),
                         make_uint2(m1a.z, m1a.w));
        uint4 h1v = gate8(gate8(aa1, ab1, make_uint2(m2b.x, m2b.y)),
                          gate8(ba1, bb1, make_uint2(m2b.z, m2b.w)),
                          make_uint2(m1b.z, m1b.w));
        *(uint4*)(sm + SM_H2 + ((uint32_t)g0 << 4)) = h0;
        *(uint4*)(sm + SM_H2 + ((uint32_t)g1 << 4)) = h1v;
    }
}

// Stage D body: layer 3 + grouped sum into csum (atomics from lane 63).
// Lane map per 128-gate chunk: gc+lane and gc+64+lane (coalesced d3M loads,
// sum-invariant: chunk lies in one class, 128 | 1024).
__device__ __forceinline__ void stage_d(char* sm, int t,
                                        const uint4* __restrict__ d3M,
                                        float* csum) {
    const int wv = t >> 6, lane = t & 63;
    const int gbase = wv * 640;
    const int cA = gbase >> 10;
    const int bnd = (cA + 1) << 10;
    const bool cross = (gbase + 640 > bnd);  // wave-uniform
    float s0[8] = {0.f, 0.f, 0.f, 0.f, 0.f, 0.f, 0.f, 0.f};
    float s1[8] = {0.f, 0.f, 0.f, 0.f, 0.f, 0.f, 0.f, 0.f};
#pragma unroll
    for (int j = 0; j < 5; ++j) {
        int gc = gbase + (j << 7);
        uint4 ma = d3M[gc + lane];
        uint4 mb = d3M[gc + 64 + lane];
        uint4 av0 = *(const uint4*)(sm + SM_H2 + ((ma.x & 0xffffu) << 4));
        uint4 bv0 = *(const uint4*)(sm + SM_H2 + ((ma.x >> 16) << 4));
        uint4 av1 = *(const uint4*)(sm + SM_H2 + ((mb.x & 0xffffu) << 4));
        uint4 bv1 = *(const uint4*)(sm + SM_H2 + ((mb.x >> 16) << 4));
        uint4 h0 = gate8(av0, bv0, make_uint2(ma.y, ma.z));
        uint4 h1v = gate8(av1, bv1, make_uint2(mb.y, mb.z));
        float pr8[8];
#pragma unroll
        for (int i = 0; i < 4; ++i) {
            __half2 pr = __hadd2(__builtin_bit_cast(__half2, (&h0.x)[i]),
                                 __builtin_bit_cast(__half2, (&h1v.x)[i]));
            pr8[2 * i] = __low2float(pr);
            pr8[2 * i + 1] = __high2float(pr);
        }
        if (gc < bnd) {  // wave-uniform per unrolled j, static indexing
#pragma unroll
            for (int r = 0; r < 8; ++r) s0[r] += pr8[r];
        } else {
#pragma unroll
            for (int r = 0; r < 8; ++r) s1[r] += pr8[r];
        }
    }
#pragma unroll
    for (int r = 0; r < 8; ++r) s0[r] = dpp_sum_f32(s0[r]);
    if (cross) {
#pragma unroll
        for (int r = 0; r < 8; ++r) s1[r] = dpp_sum_f32(s1[r]);
    }
    if (lane == 63) {
#pragma unroll
        for (int r = 0; r < 8; ++r) atomicAdd(&csum[cA * 8 + r], s0[r]);
        if (cross) {
#pragma unroll
            for (int r = 0; r < 8; ++r) atomicAdd(&csum[(cA + 1) * 8 + r], s1[r]);
        }
    }
}

// Single cooperative kernel: prep phase (metadata softmaxes, 136 tasks/block,
// hidden under the block's 16 x-row HBM loads) -> grid.sync() -> fused body
// (two pipelined 8-row passes). Removes the prep launch + ramp/tail and the
// serial prep->fused stream dependency.
__global__ __launch_bounds__(1024, 4) void fused_all(
    const float* __restrict__ x,
    const float* __restrict__ w1, const float* __restrict__ w2,
    const float* __restrict__ w3,
    const int* __restrict__ ia1, const int* __restrict__ ib1,
    const int* __restrict__ ia2, const int* __restrict__ ib2,
    const int* __restrict__ ia3, const int* __restrict__ ib3,
    uint4* __restrict__ bcM1, uint4* __restrict__ bcM2,
    uint4* __restrict__ d3M, float* __restrict__ out) {
    extern __shared__ char sm[];
    uint4* xb = (uint4*)(sm + SM_XB);
    float* csum = (float*)(sm + SM_CSUM);

    const int t = threadIdx.x;
    const int rowbase = blockIdx.x << 4;  // 16 rows per block

    // Issue all 16 x-row loads first (metadata-independent; HBM latency
    // hides under the prep softmaxes below).
    const float* xp = x + (size_t)rowbase * D0 + t;
    float x1r[8], x2r[8];
#pragma unroll
    for (int i = 0; i < 8; ++i) x1r[i] = xp[(size_t)i * D0];
#pragma unroll
    for (int i = 0; i < 8; ++i) x2r[i] = xp[(size_t)(8 + i) * D0];

    // Prep phase: one softmax task per thread, 136 tasks/block (balanced).
    //  bcM1[g] = (xiA, xiB, coO.lo, coO.hi)  xi* = packed x BYTE offsets
    //  bcM2[g] = (cA.lo, cA.hi, cB.lo, cB.hi)
    //  d3M[g]  = (ei, co.lo, co.hi, 0)       ei = packed h2 ELEMENT indices
    if (t < PREP_PER_BLOCK) {
        int T = blockIdx.x * PREP_PER_BLOCK + t;
        if (T < D2) {  // role O
            int g = T;
            int pa = ia2[g], pb = ib2[g];
            float4 cO = softmax_coef(w2 + (size_t)g * 16);
            uint32_t xiA = (uint32_t)(ia1[pa] << 4) | ((uint32_t)(ib1[pa] << 4) << 16);
            uint32_t xiB = (uint32_t)(ia1[pb] << 4) | ((uint32_t)(ib1[pb] << 4) << 16);
            uint2 o = pack_coef(cO);
            bcM1[g] = make_uint4(xiA, xiB, o.x, o.y);
        } else if (T < 2 * D2) {  // role A
            int g = T - D2;
            int pa = ia2[g];
            uint2 a = pack_coef(softmax_coef(w1 + (size_t)pa * 16));
            ((uint2*)bcM2)[2 * g] = a;
        } else if (T < 3 * D2) {  // role B
            int g = T - 2 * D2;
            int pb = ib2[g];
            uint2 b = pack_coef(softmax_coef(w1 + (size_t)pb * 16));
            ((uint2*)bcM2)[2 * g + 1] = b;
        } else {  // layer-3 gate
            int g = T - 3 * D2;
            float4 cO = softmax_coef(w3 + (size_t)g * 16);
            uint2 o = pack_coef(cO);
            uint32_t ei = (uint32_t)ia3[g] | ((uint32_t)ib3[g] << 16);
            d3M[g] = make_uint4(ei, o.x, o.y, 0u);
        }
    }

    // Stage xb rows 0-7 (block-local; grid.sync doubles as __syncthreads).
    {
        uint4 v;
#pragma unroll
        for (int i = 0; i < 4; ++i)
            (&v.x)[i] = __builtin_bit_cast(
                uint32_t, __floats2half2_rn(x1r[2 * i], x1r[2 * i + 1]));
        xb[t] = v;
    }
    if (t < 80) csum[t] = 0.f;

    // Device-scope release of the metadata writes (cross-XCD L2 writeback),
    // then grid-wide barrier.
    __threadfence();
    cg::this_grid().sync();

    // Preload iter-0 index metadata for BC pass 1 (L2-warm after prep).
    uint4 m1a_n = bcM1[t];
    uint4 m1b_n = bcM1[t + 1024];

    // ---- pass 1 (rows 0-7) ----
    stage_bc(sm, t, bcM1, bcM2, m1a_n, m1b_n);
    __syncthreads();  // h2 ready; all xb reads done -> xb region now dead

    // Stage A for pass 2: cvt held regs, write xb (overlaps with stage D).
    {
        uint4 v;
#pragma unroll
        for (int i = 0; i < 4; ++i)
            (&v.x)[i] = __builtin_bit_cast(
                uint32_t, __floats2half2_rn(x2r[2 * i], x2r[2 * i + 1]));
        xb[t] = v;
    }
    // Preload iter-0 metadata for BC pass 2 (L2-warm, hidden under stage D).
    m1a_n = bcM1[t];
    m1b_n = bcM1[t + 1024];

    stage_d(sm, t, d3M, csum);
    __syncthreads();  // csum ready; h2 reads done; xb(pass2) writes visible

    if (t < 80) {
        int c = t >> 3, r = t & 7;
        out[(size_t)(rowbase + r) * 10 + c] = csum[t] * (1.0f / 30.0f);
        csum[t] = 0.f;  // reset for pass 2 (visible after post-BC2 barrier)
    }

    // ---- pass 2 (rows 8-15) ----
    stage_bc(sm, t, bcM1, bcM2, m1a_n, m1b_n);
    __syncthreads();  // h2(pass2) ready; csum reset visible

    stage_d(sm, t, d3M, csum);
    __syncthreads();

    if (t < 80) {
        int c = t >> 3, r = t & 7;
        out[(size_t)(rowbase + 8 + r) * 10 + c] = csum[t] * (1.0f / 30.0f);
    }
}

extern "C" void kernel_launch(void* const* d_in, const int* in_sizes, int n_in,
                              void* d_out, int out_size, void* d_ws, size_t ws_size,
                              hipStream_t stream) {
    const float* x = (const float*)d_in[0];
    const float* w1 = (const float*)d_in[1];
    const float* w2 = (const float*)d_in[2];
    const float* w3 = (const float*)d_in[3];
    const int* ia1 = (const int*)d_in[4];
    const int* ib1 = (const int*)d_in[5];
    const int* ia2 = (const int*)d_in[6];
    const int* ib2 = (const int*)d_in[7];
    const int* ia3 = (const int*)d_in[8];
    const int* ib3 = (const int*)d_in[9];
    float* out = (float*)d_out;

    // Workspace: bcM1 128K | bcM2 128K | d3M 160K (all 16B-aligned).
    char* p = (char*)d_ws;
    uint4* bcM1 = (uint4*)p;    p += (size_t)D2 * 16;
    uint4* bcM2 = (uint4*)p;    p += (size_t)D2 * 16;
    uint4* d3M = (uint4*)p;

    // >64KB dynamic LDS opt-in (host-side; graph-capture safe). 144.3 KB
    // fits the 160 KB/CU pool.
    hipFuncSetAttribute(reinterpret_cast<const void*>(fused_all),
                        hipFuncAttributeMaxDynamicSharedMemorySize, SM_BYTES);

    // Cooperative launch: 256 blocks = exactly 1/CU (co-resident by
    // construction: 144.3 KB LDS -> 1 block/CU, 256 CUs).
    void* args[] = {(void*)&x,   (void*)&w1,  (void*)&w2,  (void*)&w3,
                    (void*)&ia1, (void*)&ib1, (void*)&ia2, (void*)&ib2,
                    (void*)&ia3, (void*)&ib3, (void*)&bcM1, (void*)&bcM2,
                    (void*)&d3M, (void*)&out};
    hipLaunchCooperativeKernel(reinterpret_cast<const void*>(fused_all),
                               dim3(B_ROWS / 16), dim3(1024), args, SM_BYTES,
                               stream);
}

// Round 4
// 99.258 us; speedup vs baseline: 2.1990x; 2.1990x over previous
//
#include <hip/hip_runtime.h>
#include <hip/hip_fp16.h>
#include <stdint.h>

#define D0 1024
#define D1 8192
#define D2 8192
#define D3 10240
#define B_ROWS 4096

// LDS layout (bytes), 8 rows fp16 row-interleaved [gate][8 rows]=16B:
// xb 16K | h2 128K | csum 320 -> 144.3 KB, 1 block/CU. One block covers
// 16 rows in two pipelined 8-row passes.
// NOTE (R3 post-mortem): cooperative single-launch (grid.sync) was +80us of
// stall on this shape -> two plain launches is the right structure.
#define SM_XB     0
#define SM_H2     16384
#define SM_CSUM   (16384 + 131072)
#define SM_BYTES  (16384 + 131072 + 320)

// prep tasks: 3 softmax roles per D2 gate + 1 per D3 gate = 34816 tasks.
// v3: FOUR lanes per task (quad-split softmax) -> 139264 threads, 544 blocks
// of 256 -> ~2.1 blocks/CU, 8.5 waves/CU (vs 136 blocks covering only half
// the CUs). 4x shorter exp/coef chain per lane; dependent index loads hidden
// by TLP.
#define PREP_TOTAL (3 * D2 + D3)

// Quad-split softmax(w[16]) @ OP_COEF. Lane q of each 4-lane group handles
// rows 4q..4q+3; max/sum/coef partials reduced with __shfl_xor 1,2.
// All 4 lanes return the full (c0,c1,c2,c3).
__device__ __forceinline__ float4 softmax_coef_quad(
    const float* __restrict__ w, int q) {
    float4 v = ((const float4*)w)[q];
    float m = fmaxf(fmaxf(v.x, v.y), fmaxf(v.z, v.w));
    m = fmaxf(m, __shfl_xor(m, 1, 64));
    m = fmaxf(m, __shfl_xor(m, 2, 64));
    float e0 = __expf(v.x - m), e1 = __expf(v.y - m);
    float e2 = __expf(v.z - m), e3 = __expf(v.w - m);
    float s = e0 + e1 + e2 + e3;
    s += __shfl_xor(s, 1, 64);
    s += __shfl_xor(s, 2, 64);
    float inv = 1.f / s;
    float p0 = e0 * inv, p1 = e1 * inv, p2 = e2 * inv, p3 = e3 * inv;
    // Per-quad-lane partial coefs (OPC rows 4q..4q+3; entries in {0,±1,±2}).
    float c0, c1, c2, c3;
    switch (q) {
      case 0:  c0 = 0.f;               c1 = p2 + p3;   c2 = 0.f;                 c3 = p1 - p2;              break;
      case 1:  c0 = 0.f;               c1 = p2 + p3;   c2 = p0 + p1 + p2 + p3;   c3 = -p0 - 2.f * p2 - p3;  break;
      case 2:  c0 = p0 + p1 + p2 + p3; c1 = -p0 - p1;  c2 = -(p0 + p1 + p2 + p3);c3 = p0 + 2.f * p1 + p3;   break;
      default: c0 = p0 + p1 + p2 + p3; c1 = -p0 - p1;  c2 = 0.f;                 c3 = p1 - p2;              break;
    }
    c0 += __shfl_xor(c0, 1, 64); c0 += __shfl_xor(c0, 2, 64);
    c1 += __shfl_xor(c1, 1, 64); c1 += __shfl_xor(c1, 2, 64);
    c2 += __shfl_xor(c2, 1, 64); c2 += __shfl_xor(c2, 2, 64);
    c3 += __shfl_xor(c3, 1, 64); c3 += __shfl_xor(c3, 2, 64);
    return make_float4(c0, c1, c2, c3);
}

__device__ __forceinline__ uint2 pack_coef(float4 c) {
    uint2 r;
    r.x = __builtin_bit_cast(uint32_t, __floats2half2_rn(c.x, c.y));
    r.y = __builtin_bit_cast(uint32_t, __floats2half2_rn(c.z, c.w));
    return r;
}

// prep: run-invariant metadata, packed for dwordx4 consumption.
//  bcM1[g] = (xiA, xiB, coO.lo, coO.hi)  xi* = packed x BYTE offsets
//  bcM2[g] = (cA.lo, cA.hi, cB.lo, cB.hi)
//  d3M[g]  = (ei, co.lo, co.hi, 0)       ei = packed h2 ELEMENT indices
__global__ __launch_bounds__(256) void prep_kernel(
    const float* __restrict__ w1, const float* __restrict__ w2,
    const float* __restrict__ w3,
    const int* __restrict__ ia1, const int* __restrict__ ib1,
    const int* __restrict__ ia2, const int* __restrict__ ib2,
    const int* __restrict__ ia3, const int* __restrict__ ib3,
    uint4* __restrict__ bcM1, uint4* __restrict__ bcM2,
    uint4* __restrict__ d3M) {
    int tid = blockIdx.x * 256 + threadIdx.x;
    int T = tid >> 2;           // softmax task
    int q = tid & 3;            // lane in quad
    int lane = threadIdx.x & 63;
    int qbase = lane & ~3;      // first lane of this quad

    if (T < D2) {  // role O: outer coefs + packed x byte offsets
        int g = T;
        int pa = ia2[g], pb = ib2[g];
        // Each lane fetches one of the 4 layer-1 input indices.
        int myi;
        switch (q) {
          case 0:  myi = ia1[pa]; break;
          case 1:  myi = ib1[pa]; break;
          case 2:  myi = ia1[pb]; break;
          default: myi = ib1[pb]; break;
        }
        uint32_t sh = (uint32_t)(myi << 4);
        uint32_t i0 = __shfl(sh, qbase + 0, 64);
        uint32_t i1 = __shfl(sh, qbase + 1, 64);
        uint32_t i2 = __shfl(sh, qbase + 2, 64);
        uint32_t i3 = __shfl(sh, qbase + 3, 64);
        float4 cO = softmax_coef_quad(w2 + (size_t)g * 16, q);
        if (q == 0) {
            uint2 o = pack_coef(cO);
            bcM1[g] = make_uint4(i0 | (i1 << 16), i2 | (i3 << 16), o.x, o.y);
        }
    } else if (T < 2 * D2) {  // role A
        int g = T - D2;
        int pa = ia2[g];
        float4 cA = softmax_coef_quad(w1 + (size_t)pa * 16, q);
        if (q == 0) ((uint2*)bcM2)[2 * g] = pack_coef(cA);
    } else if (T < 3 * D2) {  // role B
        int g = T - 2 * D2;
        int pb = ib2[g];
        float4 cB = softmax_coef_quad(w1 + (size_t)pb * 16, q);
        if (q == 0) ((uint2*)bcM2)[2 * g + 1] = pack_coef(cB);
    } else {  // layer-3 gate
        int g = T - 3 * D2;
        float4 cO = softmax_coef_quad(w3 + (size_t)g * 16, q);
        if (q == 0) {
            uint2 o = pack_coef(cO);
            uint32_t ei = (uint32_t)ia3[g] | ((uint32_t)ib3[g] << 16);
            d3M[g] = make_uint4(ei, o.x, o.y, 0u);
        }
    }
}

// One gate for 8 rows (4x half2); compact coefs (c0c1, c2c3) broadcast here.
// h = (c0 + c2*b) + a*(c1 + c3*b): 12 v_pk_fma_f16 + 4 extracts.
__device__ __forceinline__ uint4 gate8(uint4 av, uint4 bv, uint2 cf) {
    __half2 p = __builtin_bit_cast(__half2, cf.x);  // (c0,c1)
    __half2 q = __builtin_bit_cast(__half2, cf.y);  // (c2,c3)
    __half2 c0 = __low2half2(p), c1 = __high2half2(p);
    __half2 c2 = __low2half2(q), c3 = __high2half2(q);
    uint4 r;
#pragma unroll
    for (int i = 0; i < 4; ++i) {
        __half2 a = __builtin_bit_cast(__half2, (&av.x)[i]);
        __half2 b = __builtin_bit_cast(__half2, (&bv.x)[i]);
        __half2 h = __hfma2(a, __hfma2(b, c3, c1), __hfma2(b, c2, c0));
        (&r.x)[i] = __builtin_bit_cast(uint32_t, h);
    }
    return r;
}

// Full-wave f32 sum on the VALU pipe via DPP (row_shr 1/2/4/8 +
// row_bcast 15/31); result valid in lane 63. Keeps the reduction off the
// LDS pipe (the fused kernel's contended resource).
__device__ __forceinline__ float dpp_sum_f32(float x) {
#define DPPADD(ctrl, rmask)                                              \
    x += __builtin_bit_cast(float, __builtin_amdgcn_update_dpp(          \
             0, __builtin_bit_cast(int, x), (ctrl), (rmask), 0xf, true))
    DPPADD(0x111, 0xf);  // row_shr:1
    DPPADD(0x112, 0xf);  // row_shr:2
    DPPADD(0x114, 0xf);  // row_shr:4
    DPPADD(0x118, 0xf);  // row_shr:8  -> lane15 of each row = row sum
    DPPADD(0x142, 0xa);  // row_bcast:15 into rows 1,3
    DPPADD(0x143, 0xc);  // row_bcast:31 into rows 2,3 -> lane63 = total
#undef DPPADD
    return x;
}

// Stage BC body for one 8-row pass: fused layers 1+2.
// Gate map: thread t, step k handles gates t + 2048*kk and +1024, where
// kk = (k + skew) & 3 -- WAVE PHASE-SKEW: waves start at different
// iterations so their LDS-gather bursts and VALU phases interleave on the
// single per-CU LDS pipe (R3 counters: kernel is stall-bound, pipe ~50%
// idle, not LDS-throughput-bound). Gate partition is unchanged per thread.
__device__ __forceinline__ void stage_bc(char* sm, int t, int skew,
                                         const uint4* __restrict__ bcM1,
                                         const uint4* __restrict__ bcM2,
                                         uint4 m1a_n, uint4 m1b_n) {
#pragma unroll
    for (int k = 0; k < 4; ++k) {
        int kk = (k + skew) & 3;
        uint4 m1a = m1a_n, m1b = m1b_n;
        int g0 = t + (kk << 11);
        int g1 = g0 + 1024;
        uint4 m2a = bcM2[g0];
        uint4 m2b = bcM2[g1];
        if (k < 3) {  // depth-2 prefetch of the gather-address stream
            int kn = (k + 1 + skew) & 3;
            m1a_n = bcM1[t + (kn << 11)];
            m1b_n = bcM1[t + (kn << 11) + 1024];
        }
        // 8 independent b128 gathers in flight.
        uint4 aa0 = *(const uint4*)(sm + (m1a.x & 0xffffu));
        uint4 ab0 = *(const uint4*)(sm + (m1a.x >> 16));
        uint4 ba0 = *(const uint4*)(sm + (m1a.y & 0xffffu));
        uint4 bb0 = *(const uint4*)(sm + (m1a.y >> 16));
        uint4 aa1 = *(const uint4*)(sm + (m1b.x & 0xffffu));
        uint4 ab1 = *(const uint4*)(sm + (m1b.x >> 16));
        uint4 ba1 = *(const uint4*)(sm + (m1b.y & 0xffffu));
        uint4 bb1 = *(const uint4*)(sm + (m1b.y >> 16));
        uint4 h0 = gate8(gate8(aa0, ab0, make_uint2(m2a.x, m2a.y)),
                         gate8(ba0, bb0, make_uint2(m2a.z, m2a.w)),
                         make_uint2(m1a.z, m1a.w));
        uint4 h1v = gate8(gate8(aa1, ab1, make_uint2(m2b.x, m2b.y)),
                          gate8(ba1, bb1, make_uint2(m2b.z, m2b.w)),
                          make_uint2(m1b.z, m1b.w));
        *(uint4*)(sm + SM_H2 + ((uint32_t)g0 << 4)) = h0;
        *(uint4*)(sm + SM_H2 + ((uint32_t)g1 << 4)) = h1v;
    }
}

// Stage D body: layer 3 + grouped sum into csum (atomics from lane 63).
// Chunk order rotated per wave (skew5) for the same phase-interleaving
// reason; per-wave chunk set (and thus sums) unchanged.
__device__ __forceinline__ void stage_d(char* sm, int t, int skew5,
                                        const uint4* __restrict__ d3M,
                                        float* csum) {
    const int wv = t >> 6, lane = t & 63;
    const int gbase = wv * 640;
    const int cA = gbase >> 10;
    const int bnd = (cA + 1) << 10;
    const bool cross = (gbase + 640 > bnd);  // wave-uniform
    float s0[8] = {0.f, 0.f, 0.f, 0.f, 0.f, 0.f, 0.f, 0.f};
    float s1[8] = {0.f, 0.f, 0.f, 0.f, 0.f, 0.f, 0.f, 0.f};
#pragma unroll
    for (int j = 0; j < 5; ++j) {
        int jj = j + skew5; if (jj >= 5) jj -= 5;
        int gc = gbase + (jj << 7);
        uint4 ma = d3M[gc + lane];
        uint4 mb = d3M[gc + 64 + lane];
        uint4 av0 = *(const uint4*)(sm + SM_H2 + ((ma.x & 0xffffu) << 4));
        uint4 bv0 = *(const uint4*)(sm + SM_H2 + ((ma.x >> 16) << 4));
        uint4 av1 = *(const uint4*)(sm + SM_H2 + ((mb.x & 0xffffu) << 4));
        uint4 bv1 = *(const uint4*)(sm + SM_H2 + ((mb.x >> 16) << 4));
        uint4 h0 = gate8(av0, bv0, make_uint2(ma.y, ma.z));
        uint4 h1v = gate8(av1, bv1, make_uint2(mb.y, mb.z));
        float pr8[8];
#pragma unroll
        for (int i = 0; i < 4; ++i) {
            __half2 pr = __hadd2(__builtin_bit_cast(__half2, (&h0.x)[i]),
                                 __builtin_bit_cast(__half2, (&h1v.x)[i]));
            pr8[2 * i] = __low2float(pr);
            pr8[2 * i + 1] = __high2float(pr);
        }
        if (gc < bnd) {  // wave-uniform, static register indexing
#pragma unroll
            for (int r = 0; r < 8; ++r) s0[r] += pr8[r];
        } else {
#pragma unroll
            for (int r = 0; r < 8; ++r) s1[r] += pr8[r];
        }
    }
#pragma unroll
    for (int r = 0; r < 8; ++r) s0[r] = dpp_sum_f32(s0[r]);
    if (cross) {
#pragma unroll
        for (int r = 0; r < 8; ++r) s1[r] = dpp_sum_f32(s1[r]);
    }
    if (lane == 63) {
#pragma unroll
        for (int r = 0; r < 8; ++r) atomicAdd(&csum[cA * 8 + r], s0[r]);
        if (cross) {
#pragma unroll
            for (int r = 0; r < 8; ++r) atomicAdd(&csum[(cA + 1) * 8 + r], s1[r]);
        }
    }
}

// Fused: layers 1+2 fused, then layer 3 + group-sum. One block = 16 rows in
// two pipelined 8-row passes (256 blocks = exactly 1/CU):
//  - all 16 row-loads of x issue at kernel top (rows 8-15 held in 8 VGPRs)
//  - xb for pass 2 is written DURING stage D of pass 1 (xb region dead then)
//  - per-CU prologue/metadata-preload paid once.
__global__ __launch_bounds__(1024, 4) void fused_kernel(
    const float* __restrict__ x, const uint4* __restrict__ bcM1,
    const uint4* __restrict__ bcM2, const uint4* __restrict__ d3M,
    float* __restrict__ out) {
    extern __shared__ char sm[];
    uint4* xb = (uint4*)(sm + SM_XB);
    float* csum = (float*)(sm + SM_CSUM);

    const int t = threadIdx.x;
    const int wv = t >> 6;
    const int skew = wv & 3;       // BC phase skew
    const int skew5 = wv % 5;      // D phase skew
    const int rowbase = blockIdx.x << 4;  // 16 rows per block

    // Preload iter-0 index metadata for BC pass 1 (skewed start).
    uint4 m1a_n = bcM1[t + (skew << 11)];
    uint4 m1b_n = bcM1[t + (skew << 11) + 1024];

    // Stage A: issue all 16 row loads; stage rows 0-7 now, hold 8-15 in regs.
    const float* xp = x + (size_t)rowbase * D0 + t;
    float x2r[8];
#pragma unroll
    for (int i = 0; i < 8; ++i) x2r[i] = xp[(size_t)(8 + i) * D0];
    {
        uint4 v;
#pragma unroll
        for (int i = 0; i < 4; ++i) {
            float va = xp[(size_t)(2 * i) * D0];
            float vb = xp[(size_t)(2 * i + 1) * D0];
            (&v.x)[i] = __builtin_bit_cast(uint32_t, __floats2half2_rn(va, vb));
        }
        xb[t] = v;
    }
    if (t < 80) csum[t] = 0.f;
    __syncthreads();

    // ---- pass 1 (rows 0-7) ----
    stage_bc(sm, t, skew, bcM1, bcM2, m1a_n, m1b_n);
    __syncthreads();  // h2 ready; all xb reads done -> xb region now dead

    // Stage A for pass 2: cvt held regs, write xb (overlaps with stage D).
    {
        uint4 v;
#pragma unroll
        for (int i = 0; i < 4; ++i)
            (&v.x)[i] = __builtin_bit_cast(
                uint32_t, __floats2half2_rn(x2r[2 * i], x2r[2 * i + 1]));
        xb[t] = v;
    }
    // Preload iter-0 metadata for BC pass 2 (L2-warm, hidden under stage D).
    m1a_n = bcM1[t + (skew << 11)];
    m1b_n = bcM1[t + (skew << 11) + 1024];

    stage_d(sm, t, skew5, d3M, csum);
    __syncthreads();  // csum ready; h2 reads done; xb(pass2) writes visible

    if (t < 80) {
        int c = t >> 3, r = t & 7;
        out[(size_t)(rowbase + r) * 10 + c] = csum[t] * (1.0f / 30.0f);
        csum[t] = 0.f;  // reset for pass 2 (visible after post-BC2 barrier)
    }

    // ---- pass 2 (rows 8-15) ----
    stage_bc(sm, t, skew, bcM1, bcM2, m1a_n, m1b_n);
    __syncthreads();  // h2(pass2) ready; csum reset visible

    stage_d(sm, t, skew5, d3M, csum);
    __syncthreads();

    if (t < 80) {
        int c = t >> 3, r = t & 7;
        out[(size_t)(rowbase + 8 + r) * 10 + c] = csum[t] * (1.0f / 30.0f);
    }
}

extern "C" void kernel_launch(void* const* d_in, const int* in_sizes, int n_in,
                              void* d_out, int out_size, void* d_ws, size_t ws_size,
                              hipStream_t stream) {
    const float* x = (const float*)d_in[0];
    const float* w1 = (const float*)d_in[1];
    const float* w2 = (const float*)d_in[2];
    const float* w3 = (const float*)d_in[3];
    const int* ia1 = (const int*)d_in[4];
    const int* ib1 = (const int*)d_in[5];
    const int* ia2 = (const int*)d_in[6];
    const int* ib2 = (const int*)d_in[7];
    const int* ia3 = (const int*)d_in[8];
    const int* ib3 = (const int*)d_in[9];
    float* out = (float*)d_out;

    // Workspace: bcM1 128K | bcM2 128K | d3M 160K (all 16B-aligned).
    char* p = (char*)d_ws;
    uint4* bcM1 = (uint4*)p;    p += (size_t)D2 * 16;
    uint4* bcM2 = (uint4*)p;    p += (size_t)D2 * 16;
    uint4* d3M = (uint4*)p;

    // >64KB dynamic LDS opt-in (host-side; graph-capture safe). 144.3 KB
    // fits the 160 KB/CU pool.
    hipFuncSetAttribute(reinterpret_cast<const void*>(fused_kernel),
                        hipFuncAttributeMaxDynamicSharedMemorySize, SM_BYTES);

    // 4 lanes per softmax task: 4*34816 threads in 544 blocks of 256.
    prep_kernel<<<(4 * PREP_TOTAL) / 256, 256, 0, stream>>>(
        w1, w2, w3, ia1, ib1, ia2, ib2, ia3, ib3, bcM1, bcM2, d3M);
    fused_kernel<<<B_ROWS / 16, 1024, SM_BYTES, stream>>>(x, bcM1, bcM2, d3M, out);
}